// Round 9
// baseline (627.079 us; speedup 1.0000x reference)
//
#include <hip/hip_runtime.h>
#include <hip/hip_bf16.h>
#include <cstdint>

#define B_   32
#define CIN  12
#define L_   1024
#define T_   64
#define C1_  64
#define C2_  128
#define K_   7
#define PAD_ 3

typedef __attribute__((ext_vector_type(8))) short short8;
typedef __attribute__((ext_vector_type(4))) float float4v;

// ---- workspace layout (bytes) ----
// s1T : bf16 [B][L][half(2)][T][32]  = 268,435,456   (c1 PERMUTED within each 32: pos = kq*8+e*4+r)
// w2hi: bf16 A-frag-linear            = 114,688
// w1f : bf16 A-frag-linear [cp2][ks4][mf4][lane64][j8] = 32,768
// pool: f32  [B][C2]                  = 16,384   (fused avg-pool accumulator, zeroed by K0a)
// zp  : 4,096 B zero page (OOB halo rows for K2's global_load_lds staging)
#define WS_S1T   0ull
#define WS_W2HI  268435456ull
#define WS_W1F   (WS_W2HI + 114688ull)
#define WS_POOL  (WS_W1F + 32768ull)
#define WS_ZP    (WS_POOL + 16384ull)

// global_load_lds: LDS dest is wave-uniform base + lane*16 (linear); global src is
// per-lane (pre-swizzled). size must be a literal 16.
#define GLOAD_LDS(SRC, DST)                                                        \
    __builtin_amdgcn_global_load_lds(                                              \
        (const __attribute__((address_space(1))) unsigned int*)(const void*)(SRC), \
        (__attribute__((address_space(3))) unsigned int*)(void*)(DST), 16, 0, 0)

static __device__ __forceinline__ ushort bf16_hi(float f) {
    __hip_bfloat16 h = __float2bfloat16(f);
    ushort u; __builtin_memcpy(&u, &h, 2); return u;
}
static __device__ __forceinline__ float bf16_back(ushort u) {
    __hip_bfloat16 h; __builtin_memcpy(&h, &u, 2); return __bfloat162float(h);
}

// ---------------- K0a: w2 -> bf16, A-fragment-linear layout (+ zero pool & zero page) ----------------
__global__ __launch_bounds__(256) void k0_prep_w2(const float* __restrict__ w2,
                                                  ushort* __restrict__ w2hi,
                                                  float* __restrict__ pool,
                                                  ushort* __restrict__ zp) {
    int i = blockIdx.x * 256 + threadIdx.x;
    if (i < B_ * C2_) pool[i] = 0.0f;            // stream-ordered before K2's atomics
    if (i < 2048) zp[i] = 0;                     // 4KB zero page for K2 DMA staging
    if (i >= C2_ * K_ * C1_) return;
    int c2 = i / (K_ * C1_);
    int r_ = i % (K_ * C1_);
    int kk = r_ / C1_;
    int c1 = r_ % C1_;
    float w = w2[(c2 * C1_ + c1) * K_ + kk];
    ushort uh = bf16_hi(w);
    int h    = c1 >> 5;
    int c1r  = c1 & 31;
    int e    = c1r >> 4;
    int kq   = (c1r >> 2) & 3;
    int rr   = c1r & 3;
    int j    = e * 4 + rr;
    int mt   = c2 >> 4;
    int lane = kq * 16 + (c2 & 15);
    int o    = ((((kk * 2 + h) * 8 + mt) * 64) + lane) * 8 + j;
    w2hi[o] = uh;
}

// ---------------- K0b: w1 -> bf16 hi/lo, A-fragment-linear for conv1 MFMA ----------------
__global__ __launch_bounds__(256) void k0_prep_w1(const float* __restrict__ w1,
                                                  ushort* __restrict__ w1f) {
    int i = blockIdx.x * 256 + threadIdx.x;      // [cp2][ks4][mf4][lane64][j8] = 16384
    if (i >= 16384) return;
    int j    = i & 7;
    int lane = (i >> 3) & 63;
    int mf   = (i >> 9) & 3;
    int ks   = (i >> 11) & 3;
    int cp   = i >> 13;
    int k    = ks * 32 + (lane >> 4) * 8 + j;
    int dl   = k >> 4;
    int slot = k & 15;
    int c1   = mf * 16 + (lane & 15);
    float v  = (slot < CIN && dl < K_) ? w1[(c1 * CIN + slot) * K_ + dl] : 0.0f;
    ushort hi = bf16_hi(v);
    float  rem = v - bf16_back(hi);
    ushort lo = bf16_hi(rem);
    w1f[i] = cp ? lo : hi;
}

// ---------------- K1: conv1 via bf16 MFMA + LIF1 spike -> s1t ----------------
// R9: x-lo term DROPPED (was ah*bh + al*bh + ah*bl; now ah*bh + al*bh). Error budget:
// x bf16 roundoff 2^-9 -> conv1 err std ~sqrt(84)*0.1*2e-3 ~ 0.0018 vs pre-act spread
// ~0.92 -> ~0.16% s1 flips -> out absmax contribution ~1-2e-3 (threshold 1.28e-2;
// w1 KEEPS hi/lo — its error is systematic per-channel). Compounds: MFMA/wave 192->128,
// LDS 40,960 -> 20,480 B (no lo plane), stage VALU ~5x less, bl reads gone.
// Shape unchanged otherwise: 4 waves, wave = one l, register-direct permuted s1t store.
__global__ __launch_bounds__(256, 2) void k1_conv1_mfma(const float* __restrict__ x,
                                                        const ushort* __restrict__ w1f,
                                                        const float* __restrict__ b1,
                                                        ushort* __restrict__ s1t) {
    __shared__ __align__(16) ushort S[10 * 1024];    // 20,480 B (hi plane only)
    int tid  = threadIdx.x;
    int lane = tid & 63;
    int wl   = tid >> 6;
    int b    = blockIdx.y;
    int bx   = blockIdx.x;
    int swz  = ((bx & 7) << 5) | (bx >> 3);          // XCD swizzle, bijective (256 = 8*32)
    int lb   = swz * 4;

    #pragma unroll
    for (int it = 0; it < 5; ++it) {
        int u  = it * 256 + tid;                     // 10*2*64 = 1280 exactly
        int t  = u & 63;
        int h2 = (u >> 6) & 1;
        int lp = u >> 7;
        int gl = lb + lp - PAD_;
        bool ok = (gl >= 0) && (gl < L_);
        short8 hv;
        #pragma unroll
        for (int jj = 0; jj < 8; ++jj) {
            int cin = h2 * 8 + jj;
            float v = (ok && cin < CIN)
                ? x[(((size_t)b * CIN + cin) * L_ + gl) * T_ + t] : 0.0f;
            hv[jj] = (short)bf16_hi(v);
        }
        int nt = t >> 4, t15 = t & 15;
        *(short8*)&S[lp * 1024 + nt * 256 + h2 * 128 + t15 * 8] = hv;
    }
    __syncthreads();

    int t15 = lane & 15;
    int h2l = (lane >> 4) & 1;
    int kqh = lane >> 5;

    float4v acc[4][4];                               // constant indices ONLY
    #pragma unroll
    for (int i = 0; i < 4; ++i)
        #pragma unroll
        for (int jn = 0; jn < 4; ++jn)
            acc[i][jn] = (float4v){0.0f, 0.0f, 0.0f, 0.0f};

    #pragma unroll
    for (int ks = 0; ks < 4; ++ks) {
        int dtap = ks * 2 + kqh;
        int lpr  = (dtap == 7) ? 0 : (wl + dtap);    // dl==7: A is zero, row 0 is finite
        int rb   = lpr * 1024 + h2l * 128 + t15 * 8;
        short8 bh[4];
        #pragma unroll
        for (int nt = 0; nt < 4; ++nt)
            bh[nt] = *(const short8*)&S[rb + nt * 256];
        #pragma unroll
        for (int mf = 0; mf < 4; ++mf) {
            const ushort* ap = w1f + ((size_t)(ks * 4 + mf) * 64 + lane) * 8;
            short8 ah = *(const short8*)ap;
            short8 al = *(const short8*)(ap + 8192);     // cp=1 (w1-lo) half
            #pragma unroll
            for (int nt = 0; nt < 4; ++nt) {
                acc[mf][nt] = __builtin_amdgcn_mfma_f32_16x16x32_bf16(ah, bh[nt], acc[mf][nt], 0, 0, 0);
                acc[mf][nt] = __builtin_amdgcn_mfma_f32_16x16x32_bf16(al, bh[nt], acc[mf][nt], 0, 0, 0);
            }
        }
    }

    // spike <=> conv + b1 >= TH1/GAIN = 0.25 (LIF1 tau=1 is memoryless).
    int l  = lb + wl;
    int kq = lane >> 4;
    #pragma unroll
    for (int h = 0; h < 2; ++h) {
        float4v be0 = *(const float4v*)&b1[h * 32 + kq * 4];
        float4v be1 = *(const float4v*)&b1[h * 32 + 16 + kq * 4];
        #pragma unroll
        for (int nt = 0; nt < 4; ++nt) {
            uint s0 = (acc[2 * h][nt][0] + be0[0] >= 0.25f) ? 0x3F80u : 0u;
            uint s1 = (acc[2 * h][nt][1] + be0[1] >= 0.25f) ? 0x3F80u : 0u;
            uint s2 = (acc[2 * h][nt][2] + be0[2] >= 0.25f) ? 0x3F80u : 0u;
            uint s3 = (acc[2 * h][nt][3] + be0[3] >= 0.25f) ? 0x3F80u : 0u;
            uint s4 = (acc[2 * h + 1][nt][0] + be1[0] >= 0.25f) ? 0x3F80u : 0u;
            uint s5 = (acc[2 * h + 1][nt][1] + be1[1] >= 0.25f) ? 0x3F80u : 0u;
            uint s6 = (acc[2 * h + 1][nt][2] + be1[2] >= 0.25f) ? 0x3F80u : 0u;
            uint s7 = (acc[2 * h + 1][nt][3] + be1[3] >= 0.25f) ? 0x3F80u : 0u;
            uint4 u4 = { s0 | (s1 << 16), s2 | (s3 << 16),
                         s4 | (s5 << 16), s6 | (s7 << 16) };
            size_t off = ((((size_t)b * L_ + l) * 2 + h) * T_ + (nt * 16 + t15)) * 32 + kq * 8;
            *(uint4*)&s1t[off] = u4;
        }
    }
}

// ---------------- K2: conv2 (bf16 MFMA) + fused LIF2 + fused avg-pool ----------------
// R9: reverted to R7-exact (294 us, proven twice). R8's counted-vmcnt dbuf was -19 us —
// falsified "barrier drain is binding"; the plateau is in-loop latency, not sync.
// DMA staging (global_load_lds, pre-swizzled source), sequential h phases, 2 barriers/h.
// INVARIANT: acc[][] indexed with compile-time constants ONLY (scratch-demotion hazard).
__global__ __launch_bounds__(512, 2) void k2_conv2_lif(const ushort* __restrict__ s1t,
                                                       const ushort* __restrict__ w2hi,
                                                       const float* __restrict__ b2,
                                                       float* __restrict__ pool,
                                                       const ushort* __restrict__ zp) {
    __shared__ __align__(16) unsigned char lds_raw[40960];
    ushort* S = (ushort*)lds_raw;   // stage: [lp10][nt4][kq4][t15 16][j8] = 40,960 B (one h)
    int tid    = threadIdx.x;
    int wv     = tid >> 6;          // 0..7
    int lane   = tid & 63;
    int wn     = wv >> 1;           // l offset 0..3: l = lb + wn
    int wm     = wv & 1;            // m half: c2 in [wm*64, wm*64+64)
    int b      = blockIdx.y;
    int bx     = blockIdx.x;
    int swz    = ((bx & 7) << 5) | (bx >> 3);   // bijective XCD swizzle (256 = 8*32)
    int lb     = swz * 4;
    int lane15 = lane & 15;
    int kq     = lane >> 4;
    int srcoff = lane15 * 32 + (lane >> 4) * 8; // pre-swizzled DMA source (ushorts)

    float4v acc[4][4];             // [m-frag][n-frag], 64 regs — constant indices ONLY
    #pragma unroll
    for (int i = 0; i < 4; ++i)
        #pragma unroll
        for (int j = 0; j < 4; ++j)
            acc[i][j] = (float4v){0.0f, 0.0f, 0.0f, 0.0f};

    #pragma unroll 1
    for (int h = 0; h < 2; ++h) {
        __syncthreads();           // S reads of previous h done
        // DMA stage: rows lb-3..lb+6 (10 x 4KB); wave-uniform row loop, 4 insts/row
        #pragma unroll
        for (int r0 = 0; r0 < 2; ++r0) {
            int r = r0 * 8 + wv;
            if (r < 10) {
                int gl = lb + r - PAD_;
                const ushort* srow = (gl >= 0 && gl < L_)
                    ? &s1t[(((size_t)b * L_ + gl) * 2 + h) * 2048] : zp;
                const ushort* s = srow + srcoff;
                ushort* d = &S[r * 2048];
                GLOAD_LDS(s,        d);
                GLOAD_LDS(s + 512,  d + 512);
                GLOAD_LDS(s + 1024, d + 1024);
                GLOAD_LDS(s + 1536, d + 1536);
            }
        }
        __syncthreads();           // emits vmcnt(0) drain: DMA complete for all waves
        #pragma unroll 2
        for (int kk = 0; kk < K_; ++kk) {
            int lp = wn + kk;            // staged row feeding output l = lb+wn at tap kk
            short8 bf[4];
            #pragma unroll
            for (int nt = 0; nt < 4; ++nt)   // lane-linear 2KB frag -> conflict-free b128
                bf[nt] = *(const short8*)&S[lp * 2048 + nt * 512 + lane * 8];
            #pragma unroll
            for (int mf = 0; mf < 4; ++mf) {
                int aoff = (((kk * 2 + h) * 8 + wm * 4 + mf) * 64 + lane) * 8;  // 32-bit
                short8 ahi = *(const short8*)&w2hi[aoff];
                #pragma unroll
                for (int nt = 0; nt < 4; ++nt)
                    acc[mf][nt] = __builtin_amdgcn_mfma_f32_16x16x32_bf16(ahi, bf[nt], acc[mf][nt], 0, 0, 0);
            }
        }
    }
    __syncthreads();    // all S reads done before epilogue overlays the region

    // ---- epilogue: streaming transpose (one nt = 16 t-rows at a time) + LIF2 scan ----
    // E[t15 16][68]: b128 stores slot=(lane15+kq+4mfl)%8 -> 8 lanes/slot, conflict-free;
    // reads bank (4t+lane)%32 -> 2-way (free). All 64 lanes scan (c2 = wm*64 + lane).
    // Scan: v' = A*v + (E*Cs + D), A = 1-1/0.9, Cs = 2/0.9, D = bias*2/0.9.
    float* E = ((float*)lds_raw) + wv * 1088;
    int c2v = wm * 64 + lane;
    const float Af = 1.0f - 1.0f / 0.9f;
    const float Cs = 2.0f / 0.9f;
    float D = b2[c2v] * Cs;
    float v = 0.0f;
    uint cnt = 0u;
    #pragma unroll
    for (int nt = 0; nt < 4; ++nt) {
        *(float4v*)&E[lane15 * 68 + 0 * 16 + kq * 4] = acc[0][nt];   // D: col t = nt*16+lane15
        *(float4v*)&E[lane15 * 68 + 1 * 16 + kq * 4] = acc[1][nt];   //    row c2l = mfl*16+kq*4+r
        *(float4v*)&E[lane15 * 68 + 2 * 16 + kq * 4] = acc[2][nt];
        *(float4v*)&E[lane15 * 68 + 3 * 16 + kq * 4] = acc[3][nt];
        __builtin_amdgcn_s_waitcnt(0);           // wave-local LDS RAW
        #pragma unroll
        for (int tt = 0; tt < 16; ++tt) {
            float e = fmaf(E[tt * 68 + lane], Cs, D);
            v = fmaf(Af, v, e);
            bool sp = (v >= 0.5f);
            cnt += sp ? 1u : 0u;
            v = sp ? 0.0f : v;
        }
        __builtin_amdgcn_s_waitcnt(0);           // reads done before next nt overwrites
    }
    atomicAdd(&pool[b * C2_ + c2v], (float)cnt);  // integer-valued: exact, order-free
}

// ---------------- K3: fc on pooled [B][C2] (pool already summed over l,t) ----------------
__global__ __launch_bounds__(128) void k3_fc(const float* __restrict__ pool,
                                             const float* __restrict__ fcw,
                                             const float* __restrict__ fcb,
                                             float* __restrict__ out) {
    int i = threadIdx.x;          // 128 = B*4 outputs
    int b = i >> 2, c = i & 3;
    float o = fcb[c];
    #pragma unroll 8
    for (int c2 = 0; c2 < C2_; ++c2)
        o = fmaf(fcw[c * C2_ + c2], pool[b * C2_ + c2] * (1.0f / 65536.0f), o);
    out[b * 4 + c] = o;
}

extern "C" void kernel_launch(void* const* d_in, const int* in_sizes, int n_in,
                              void* d_out, int out_size, void* d_ws, size_t ws_size,
                              hipStream_t stream) {
    const float* x   = (const float*)d_in[0];
    const float* w1  = (const float*)d_in[1];
    const float* b1  = (const float*)d_in[2];
    const float* w2  = (const float*)d_in[3];
    const float* b2  = (const float*)d_in[4];
    const float* fcw = (const float*)d_in[5];
    const float* fcb = (const float*)d_in[6];
    float* out = (float*)d_out;

    char* ws = (char*)d_ws;
    ushort* s1t  = (ushort*)(ws + WS_S1T);
    ushort* w2h  = (ushort*)(ws + WS_W2HI);
    ushort* w1f  = (ushort*)(ws + WS_W1F);
    float*  pool = (float*)(ws + WS_POOL);
    ushort* zp   = (ushort*)(ws + WS_ZP);

    k0_prep_w2<<<dim3((C2_ * K_ * C1_ + 255) / 256), dim3(256), 0, stream>>>(w2, w2h, pool, zp);
    k0_prep_w1<<<dim3(64), dim3(256), 0, stream>>>(w1, w1f);
    k1_conv1_mfma<<<dim3(L_ / 4, B_), dim3(256), 0, stream>>>(x, w1f, b1, s1t);
    k2_conv2_lif<<<dim3(L_ / 4, B_), dim3(512), 0, stream>>>(s1t, w2h, b2, pool, zp);
    k3_fc<<<dim3(1), dim3(128), 0, stream>>>(pool, fcw, fcb, out);
}

// Round 10
// 521.888 us; speedup vs baseline: 1.2016x; 1.2016x over previous
//
#include <hip/hip_runtime.h>
#include <hip/hip_bf16.h>
#include <cstdint>

#define B_   32
#define CIN  12
#define L_   1024
#define T_   64
#define C1_  64
#define C2_  128
#define K_   7
#define PAD_ 3

typedef __attribute__((ext_vector_type(8))) short short8;
typedef __attribute__((ext_vector_type(4))) float float4v;

// ---- workspace layout (bytes) ----
// s1T : bf16 [B][L][half(2)][T][32]  = 268,435,456   (c1 PERMUTED within each 32: pos = kq*8+e*4+r)
// w2hi: bf16 A-frag-linear            = 114,688
// w1f : bf16 A-frag-linear [cp2][ks4][mf4][lane64][j8] = 32,768
// pool: f32  [B][C2]                  = 16,384   (fused avg-pool accumulator, zeroed by K0)
// zp  : 4,096 B zero page (OOB halo rows for K2's global_load_lds staging)
#define WS_S1T   0ull
#define WS_W2HI  268435456ull
#define WS_W1F   (WS_W2HI + 114688ull)
#define WS_POOL  (WS_W1F + 32768ull)
#define WS_ZP    (WS_POOL + 16384ull)

// global_load_lds: LDS dest is wave-uniform base + lane*16 (linear); global src is
// per-lane (pre-swizzled). size must be a literal 16.
#define GLOAD_LDS(SRC, DST)                                                        \
    __builtin_amdgcn_global_load_lds(                                              \
        (const __attribute__((address_space(1))) unsigned int*)(const void*)(SRC), \
        (__attribute__((address_space(3))) unsigned int*)(void*)(DST), 16, 0, 0)

static __device__ __forceinline__ ushort bf16_hi(float f) {
    __hip_bfloat16 h = __float2bfloat16(f);
    ushort u; __builtin_memcpy(&u, &h, 2); return u;
}
static __device__ __forceinline__ float bf16_back(ushort u) {
    __hip_bfloat16 h; __builtin_memcpy(&h, &u, 2); return __bfloat162float(h);
}

// ---------------- K0: w2 + w1 prep merged (one dispatch), + zero pool & zero page ----------------
// w2: c1 contraction order PERMUTED within each 32-chunk to match K1's register-direct
// s1t store: k~ = kq*8 + e*4 + r  <->  c1r = e*16 + kq*4 + r  (e = c1r>>4).
// w1: hi/lo split, A-frag-linear, contraction k = dl*16 + cin (slots 12..15 zero).
__global__ __launch_bounds__(256) void k0_prep(const float* __restrict__ w2,
                                               ushort* __restrict__ w2hi,
                                               const float* __restrict__ w1,
                                               ushort* __restrict__ w1f,
                                               float* __restrict__ pool,
                                               ushort* __restrict__ zp) {
    int i = blockIdx.x * 256 + threadIdx.x;
    if (i < B_ * C2_) pool[i] = 0.0f;            // stream-ordered before K2's atomics
    if (i < 2048) zp[i] = 0;                     // 4KB zero page for K2 DMA staging
    if (i < 16384) {                             // ---- w1f: [cp2][ks4][mf4][lane64][j8]
        int j    = i & 7;
        int lane = (i >> 3) & 63;
        int mf   = (i >> 9) & 3;
        int ks   = (i >> 11) & 3;
        int cp   = i >> 13;
        int k    = ks * 32 + (lane >> 4) * 8 + j;
        int dl   = k >> 4;
        int slot = k & 15;
        int c1   = mf * 16 + (lane & 15);
        float v  = (slot < CIN && dl < K_) ? w1[(c1 * CIN + slot) * K_ + dl] : 0.0f;
        ushort hi = bf16_hi(v);
        float  rem = v - bf16_back(hi);
        ushort lo = bf16_hi(rem);
        w1f[i] = cp ? lo : hi;
    }
    if (i >= C2_ * K_ * C1_) return;             // ---- w2hi
    int c2 = i / (K_ * C1_);
    int r_ = i % (K_ * C1_);
    int kk = r_ / C1_;
    int c1 = r_ % C1_;
    float w = w2[(c2 * C1_ + c1) * K_ + kk];
    ushort uh = bf16_hi(w);
    int h    = c1 >> 5;
    int c1r  = c1 & 31;
    int e    = c1r >> 4;
    int kq   = (c1r >> 2) & 3;
    int rr   = c1r & 3;
    int j    = e * 4 + rr;
    int mt   = c2 >> 4;
    int lane = kq * 16 + (c2 & 15);
    int o    = ((((kk * 2 + h) * 8 + mt) * 64) + lane) * 8 + j;
    w2hi[o] = uh;
}

// ---------------- K1: conv1 via bf16 MFMA (hi/lo split) + LIF1 spike -> s1t ----------------
// R10: R6/R8-exact (3-MFMA, 256 threads, 40KB LDS) — the proven-best k1. R9's 2-MFMA
// variant measured ~+100us despite strictly less work (unexplained; reverted per rule:
// don't argue with the measurement on an unexplained regression).
__global__ __launch_bounds__(256, 2) void k1_conv1_mfma(const float* __restrict__ x,
                                                        const ushort* __restrict__ w1f,
                                                        const float* __restrict__ b1,
                                                        ushort* __restrict__ s1t) {
    __shared__ __align__(16) ushort S[10 * 2048];    // 40,960 B
    int tid  = threadIdx.x;
    int lane = tid & 63;
    int wl   = tid >> 6;
    int b    = blockIdx.y;
    int bx   = blockIdx.x;
    int swz  = ((bx & 7) << 5) | (bx >> 3);          // XCD swizzle, bijective (256 = 8*32)
    int lb   = swz * 4;

    #pragma unroll
    for (int it = 0; it < 5; ++it) {
        int u  = it * 256 + tid;                     // 10*2*64 = 1280 exactly
        int t  = u & 63;
        int h2 = (u >> 6) & 1;
        int lp = u >> 7;
        int gl = lb + lp - PAD_;
        bool ok = (gl >= 0) && (gl < L_);
        short8 hv, lv;
        #pragma unroll
        for (int jj = 0; jj < 8; ++jj) {
            int cin = h2 * 8 + jj;
            float v = (ok && cin < CIN)
                ? x[(((size_t)b * CIN + cin) * L_ + gl) * T_ + t] : 0.0f;
            ushort hb = bf16_hi(v);
            ushort lo = bf16_hi(v - bf16_back(hb));
            hv[jj] = (short)hb;
            lv[jj] = (short)lo;
        }
        int nt = t >> 4, t15 = t & 15;
        int base = lp * 2048 + nt * 256 + h2 * 128 + t15 * 8;
        *(short8*)&S[base]        = hv;              // cp=0 (hi)
        *(short8*)&S[base + 1024] = lv;              // cp=1 (lo)
    }
    __syncthreads();

    int t15 = lane & 15;
    int h2l = (lane >> 4) & 1;
    int kqh = lane >> 5;

    float4v acc[4][4];                               // constant indices ONLY
    #pragma unroll
    for (int i = 0; i < 4; ++i)
        #pragma unroll
        for (int jn = 0; jn < 4; ++jn)
            acc[i][jn] = (float4v){0.0f, 0.0f, 0.0f, 0.0f};

    #pragma unroll
    for (int ks = 0; ks < 4; ++ks) {
        int dtap = ks * 2 + kqh;
        int lpr  = (dtap == 7) ? 0 : (wl + dtap);    // dl==7: A is zero, row 0 is finite
        int rb   = lpr * 2048 + h2l * 128 + t15 * 8;
        short8 bh[4], bl[4];
        #pragma unroll
        for (int nt = 0; nt < 4; ++nt) {
            bh[nt] = *(const short8*)&S[rb + nt * 256];
            bl[nt] = *(const short8*)&S[rb + nt * 256 + 1024];
        }
        #pragma unroll
        for (int mf = 0; mf < 4; ++mf) {
            const ushort* ap = w1f + ((size_t)(ks * 4 + mf) * 64 + lane) * 8;
            short8 ah = *(const short8*)ap;
            short8 al = *(const short8*)(ap + 8192);     // cp=1 half
            #pragma unroll
            for (int nt = 0; nt < 4; ++nt) {
                acc[mf][nt] = __builtin_amdgcn_mfma_f32_16x16x32_bf16(ah, bh[nt], acc[mf][nt], 0, 0, 0);
                acc[mf][nt] = __builtin_amdgcn_mfma_f32_16x16x32_bf16(al, bh[nt], acc[mf][nt], 0, 0, 0);
                acc[mf][nt] = __builtin_amdgcn_mfma_f32_16x16x32_bf16(ah, bl[nt], acc[mf][nt], 0, 0, 0);
            }
        }
    }

    // spike <=> conv + b1 >= TH1/GAIN = 0.25 (LIF1 tau=1 is memoryless).
    int l  = lb + wl;
    int kq = lane >> 4;
    #pragma unroll
    for (int h = 0; h < 2; ++h) {
        float4v be0 = *(const float4v*)&b1[h * 32 + kq * 4];
        float4v be1 = *(const float4v*)&b1[h * 32 + 16 + kq * 4];
        #pragma unroll
        for (int nt = 0; nt < 4; ++nt) {
            uint s0 = (acc[2 * h][nt][0] + be0[0] >= 0.25f) ? 0x3F80u : 0u;
            uint s1 = (acc[2 * h][nt][1] + be0[1] >= 0.25f) ? 0x3F80u : 0u;
            uint s2 = (acc[2 * h][nt][2] + be0[2] >= 0.25f) ? 0x3F80u : 0u;
            uint s3 = (acc[2 * h][nt][3] + be0[3] >= 0.25f) ? 0x3F80u : 0u;
            uint s4 = (acc[2 * h + 1][nt][0] + be1[0] >= 0.25f) ? 0x3F80u : 0u;
            uint s5 = (acc[2 * h + 1][nt][1] + be1[1] >= 0.25f) ? 0x3F80u : 0u;
            uint s6 = (acc[2 * h + 1][nt][2] + be1[2] >= 0.25f) ? 0x3F80u : 0u;
            uint s7 = (acc[2 * h + 1][nt][3] + be1[3] >= 0.25f) ? 0x3F80u : 0u;
            uint4 u4 = { s0 | (s1 << 16), s2 | (s3 << 16),
                         s4 | (s5 << 16), s6 | (s7 << 16) };
            size_t off = ((((size_t)b * L_ + l) * 2 + h) * T_ + (nt * 16 + t15)) * 32 + kq * 8;
            *(uint4*)&s1t[off] = u4;
        }
    }
}

// ---------------- K2: conv2 (bf16 MFMA) + fused LIF2 + fused avg-pool ----------------
// R10: R9-exact (288 us — best of 5 structural variants: 326/294/294/313/288).
// DMA staging (global_load_lds, pre-swizzled source), sequential h phases, 2 barriers/h.
// INVARIANT: acc[][] indexed with compile-time constants ONLY (scratch-demotion hazard).
__global__ __launch_bounds__(512, 2) void k2_conv2_lif(const ushort* __restrict__ s1t,
                                                       const ushort* __restrict__ w2hi,
                                                       const float* __restrict__ b2,
                                                       float* __restrict__ pool,
                                                       const ushort* __restrict__ zp) {
    __shared__ __align__(16) unsigned char lds_raw[40960];
    ushort* S = (ushort*)lds_raw;   // stage: [lp10][nt4][kq4][t15 16][j8] = 40,960 B (one h)
    int tid    = threadIdx.x;
    int wv     = tid >> 6;          // 0..7
    int lane   = tid & 63;
    int wn     = wv >> 1;           // l offset 0..3: l = lb + wn
    int wm     = wv & 1;            // m half: c2 in [wm*64, wm*64+64)
    int b      = blockIdx.y;
    int bx     = blockIdx.x;
    int swz    = ((bx & 7) << 5) | (bx >> 3);   // bijective XCD swizzle (256 = 8*32)
    int lb     = swz * 4;
    int lane15 = lane & 15;
    int kq     = lane >> 4;
    int srcoff = lane15 * 32 + (lane >> 4) * 8; // pre-swizzled DMA source (ushorts)

    float4v acc[4][4];             // [m-frag][n-frag], 64 regs — constant indices ONLY
    #pragma unroll
    for (int i = 0; i < 4; ++i)
        #pragma unroll
        for (int j = 0; j < 4; ++j)
            acc[i][j] = (float4v){0.0f, 0.0f, 0.0f, 0.0f};

    #pragma unroll 1
    for (int h = 0; h < 2; ++h) {
        __syncthreads();           // S reads of previous h done
        // DMA stage: rows lb-3..lb+6 (10 x 4KB); wave-uniform row loop, 4 insts/row
        #pragma unroll
        for (int r0 = 0; r0 < 2; ++r0) {
            int r = r0 * 8 + wv;
            if (r < 10) {
                int gl = lb + r - PAD_;
                const ushort* srow = (gl >= 0 && gl < L_)
                    ? &s1t[(((size_t)b * L_ + gl) * 2 + h) * 2048] : zp;
                const ushort* s = srow + srcoff;
                ushort* d = &S[r * 2048];
                GLOAD_LDS(s,        d);
                GLOAD_LDS(s + 512,  d + 512);
                GLOAD_LDS(s + 1024, d + 1024);
                GLOAD_LDS(s + 1536, d + 1536);
            }
        }
        __syncthreads();           // emits vmcnt(0) drain: DMA complete for all waves
        #pragma unroll 2
        for (int kk = 0; kk < K_; ++kk) {
            int lp = wn + kk;            // staged row feeding output l = lb+wn at tap kk
            short8 bf[4];
            #pragma unroll
            for (int nt = 0; nt < 4; ++nt)   // lane-linear 2KB frag -> conflict-free b128
                bf[nt] = *(const short8*)&S[lp * 2048 + nt * 512 + lane * 8];
            #pragma unroll
            for (int mf = 0; mf < 4; ++mf) {
                int aoff = (((kk * 2 + h) * 8 + wm * 4 + mf) * 64 + lane) * 8;  // 32-bit
                short8 ahi = *(const short8*)&w2hi[aoff];
                #pragma unroll
                for (int nt = 0; nt < 4; ++nt)
                    acc[mf][nt] = __builtin_amdgcn_mfma_f32_16x16x32_bf16(ahi, bf[nt], acc[mf][nt], 0, 0, 0);
            }
        }
    }
    __syncthreads();    // all S reads done before epilogue overlays the region

    // ---- epilogue: streaming transpose (one nt = 16 t-rows at a time) + LIF2 scan ----
    // E[t15 16][68]: b128 stores slot=(lane15+kq+4mfl)%8 -> 8 lanes/slot, conflict-free;
    // reads bank (4t+lane)%32 -> 2-way (free). All 64 lanes scan (c2 = wm*64 + lane).
    // Scan: v' = A*v + (E*Cs + D), A = 1-1/0.9, Cs = 2/0.9, D = bias*2/0.9.
    float* E = ((float*)lds_raw) + wv * 1088;
    int c2v = wm * 64 + lane;
    const float Af = 1.0f - 1.0f / 0.9f;
    const float Cs = 2.0f / 0.9f;
    float D = b2[c2v] * Cs;
    float v = 0.0f;
    uint cnt = 0u;
    #pragma unroll
    for (int nt = 0; nt < 4; ++nt) {
        *(float4v*)&E[lane15 * 68 + 0 * 16 + kq * 4] = acc[0][nt];   // D: col t = nt*16+lane15
        *(float4v*)&E[lane15 * 68 + 1 * 16 + kq * 4] = acc[1][nt];   //    row c2l = mfl*16+kq*4+r
        *(float4v*)&E[lane15 * 68 + 2 * 16 + kq * 4] = acc[2][nt];
        *(float4v*)&E[lane15 * 68 + 3 * 16 + kq * 4] = acc[3][nt];
        __builtin_amdgcn_s_waitcnt(0);           // wave-local LDS RAW
        #pragma unroll
        for (int tt = 0; tt < 16; ++tt) {
            float e = fmaf(E[tt * 68 + lane], Cs, D);
            v = fmaf(Af, v, e);
            bool sp = (v >= 0.5f);
            cnt += sp ? 1u : 0u;
            v = sp ? 0.0f : v;
        }
        __builtin_amdgcn_s_waitcnt(0);           // reads done before next nt overwrites
    }
    atomicAdd(&pool[b * C2_ + c2v], (float)cnt);  // integer-valued: exact, order-free
}

// ---------------- K3: fc on pooled [B][C2] (pool already summed over l,t) ----------------
__global__ __launch_bounds__(128) void k3_fc(const float* __restrict__ pool,
                                             const float* __restrict__ fcw,
                                             const float* __restrict__ fcb,
                                             float* __restrict__ out) {
    int i = threadIdx.x;          // 128 = B*4 outputs
    int b = i >> 2, c = i & 3;
    float o = fcb[c];
    #pragma unroll 8
    for (int c2 = 0; c2 < C2_; ++c2)
        o = fmaf(fcw[c * C2_ + c2], pool[b * C2_ + c2] * (1.0f / 65536.0f), o);
    out[b * 4 + c] = o;
}

extern "C" void kernel_launch(void* const* d_in, const int* in_sizes, int n_in,
                              void* d_out, int out_size, void* d_ws, size_t ws_size,
                              hipStream_t stream) {
    const float* x   = (const float*)d_in[0];
    const float* w1  = (const float*)d_in[1];
    const float* b1  = (const float*)d_in[2];
    const float* w2  = (const float*)d_in[3];
    const float* b2  = (const float*)d_in[4];
    const float* fcw = (const float*)d_in[5];
    const float* fcb = (const float*)d_in[6];
    float* out = (float*)d_out;

    char* ws = (char*)d_ws;
    ushort* s1t  = (ushort*)(ws + WS_S1T);
    ushort* w2h  = (ushort*)(ws + WS_W2HI);
    ushort* w1f  = (ushort*)(ws + WS_W1F);
    float*  pool = (float*)(ws + WS_POOL);
    ushort* zp   = (ushort*)(ws + WS_ZP);

    k0_prep<<<dim3((C2_ * K_ * C1_ + 255) / 256), dim3(256), 0, stream>>>(w2, w2h, w1, w1f, pool, zp);
    k1_conv1_mfma<<<dim3(L_ / 4, B_), dim3(256), 0, stream>>>(x, w1f, b1, s1t);
    k2_conv2_lif<<<dim3(L_ / 4, B_), dim3(512), 0, stream>>>(s1t, w2h, b2, pool, zp);
    k3_fc<<<dim3(1), dim3(128), 0, stream>>>(pool, fcw, fcb, out);
}

// Round 11
// 517.970 us; speedup vs baseline: 1.2106x; 1.0076x over previous
//
#include <hip/hip_runtime.h>
#include <hip/hip_bf16.h>
#include <cstdint>

#define B_   32
#define CIN  12
#define L_   1024
#define T_   64
#define C1_  64
#define C2_  128
#define K_   7
#define PAD_ 3

typedef __attribute__((ext_vector_type(8))) short short8;
typedef __attribute__((ext_vector_type(4))) float float4v;

// ---- workspace layout (bytes) ----
// s1T : bf16 [B][L][half(2)][T][32]  = 268,435,456   (c1 PERMUTED within each 32: pos = kq*8+e*4+r)
// w2hi: bf16 A-frag-linear            = 114,688
// w1f : bf16 A-frag-linear [cp2][ks4][mf4][lane64][j8] = 32,768
// pool: f32  [B][C2]                  = 16,384   (fused avg-pool accumulator, zeroed by K0)
// zp  : 4,096 B zero page (OOB halo rows for K2's global_load_lds staging)
#define WS_S1T   0ull
#define WS_W2HI  268435456ull
#define WS_W1F   (WS_W2HI + 114688ull)
#define WS_POOL  (WS_W1F + 32768ull)
#define WS_ZP    (WS_POOL + 16384ull)

// global_load_lds: LDS dest is wave-uniform base + lane*16 (linear); global src is
// per-lane (pre-swizzled). size must be a literal 16.
#define GLOAD_LDS(SRC, DST)                                                        \
    __builtin_amdgcn_global_load_lds(                                              \
        (const __attribute__((address_space(1))) unsigned int*)(const void*)(SRC), \
        (__attribute__((address_space(3))) unsigned int*)(void*)(DST), 16, 0, 0)

static __device__ __forceinline__ ushort bf16_hi(float f) {
    __hip_bfloat16 h = __float2bfloat16(f);
    ushort u; __builtin_memcpy(&u, &h, 2); return u;
}
static __device__ __forceinline__ float bf16_back(ushort u) {
    __hip_bfloat16 h; __builtin_memcpy(&h, &u, 2); return __bfloat162float(h);
}

// ---------------- K0: w2 + w1 prep merged (one dispatch), + zero pool & zero page ----------------
// w2: c1 contraction order PERMUTED within each 32-chunk to match K1's register-direct
// s1t store: k~ = kq*8 + e*4 + r  <->  c1r = e*16 + kq*4 + r  (e = c1r>>4).
// w1: hi/lo split, A-frag-linear, contraction k = dl*16 + cin (slots 12..15 zero).
__global__ __launch_bounds__(256) void k0_prep(const float* __restrict__ w2,
                                               ushort* __restrict__ w2hi,
                                               const float* __restrict__ w1,
                                               ushort* __restrict__ w1f,
                                               float* __restrict__ pool,
                                               ushort* __restrict__ zp) {
    int i = blockIdx.x * 256 + threadIdx.x;
    if (i < B_ * C2_) pool[i] = 0.0f;            // stream-ordered before K2's atomics
    if (i < 2048) zp[i] = 0;                     // 4KB zero page for K2 DMA staging
    if (i < 16384) {                             // ---- w1f: [cp2][ks4][mf4][lane64][j8]
        int j    = i & 7;
        int lane = (i >> 3) & 63;
        int mf   = (i >> 9) & 3;
        int ks   = (i >> 11) & 3;
        int cp   = i >> 13;
        int k    = ks * 32 + (lane >> 4) * 8 + j;
        int dl   = k >> 4;
        int slot = k & 15;
        int c1   = mf * 16 + (lane & 15);
        float v  = (slot < CIN && dl < K_) ? w1[(c1 * CIN + slot) * K_ + dl] : 0.0f;
        ushort hi = bf16_hi(v);
        float  rem = v - bf16_back(hi);
        ushort lo = bf16_hi(rem);
        w1f[i] = cp ? lo : hi;
    }
    if (i >= C2_ * K_ * C1_) return;             // ---- w2hi
    int c2 = i / (K_ * C1_);
    int r_ = i % (K_ * C1_);
    int kk = r_ / C1_;
    int c1 = r_ % C1_;
    float w = w2[(c2 * C1_ + c1) * K_ + kk];
    ushort uh = bf16_hi(w);
    int h    = c1 >> 5;
    int c1r  = c1 & 31;
    int e    = c1r >> 4;
    int kq   = (c1r >> 2) & 3;
    int rr   = c1r & 3;
    int j    = e * 4 + rr;
    int mt   = c2 >> 4;
    int lane = kq * 16 + (c2 & 15);
    int o    = ((((kk * 2 + h) * 8 + mt) * 64) + lane) * 8 + j;
    w2hi[o] = uh;
}

// ---------------- K1: conv1 via bf16 MFMA (hi/lo split) + LIF1 spike -> s1t ----------------
// R11: SINGLE CHANGE vs R10 — launch_bounds (256,2) -> (256,3). Theory: k1 is ~3x its
// ~70us floor with neither pipe saturated = latency-bound; (256,2) let the allocator
// take up to 256 VGPR -> 2 waves/SIMD resident. Cap ~170 (est. need ~130) forces
// 3 waves/SIMD = 12 waves/CU (+50% latency hiding); LDS 40,960 allows 3 blocks/CU.
// Tripwire: WRITE_SIZE inflation = spill -> revert to (256,2).
__global__ __launch_bounds__(256, 3) void k1_conv1_mfma(const float* __restrict__ x,
                                                        const ushort* __restrict__ w1f,
                                                        const float* __restrict__ b1,
                                                        ushort* __restrict__ s1t) {
    __shared__ __align__(16) ushort S[10 * 2048];    // 40,960 B
    int tid  = threadIdx.x;
    int lane = tid & 63;
    int wl   = tid >> 6;
    int b    = blockIdx.y;
    int bx   = blockIdx.x;
    int swz  = ((bx & 7) << 5) | (bx >> 3);          // XCD swizzle, bijective (256 = 8*32)
    int lb   = swz * 4;

    #pragma unroll
    for (int it = 0; it < 5; ++it) {
        int u  = it * 256 + tid;                     // 10*2*64 = 1280 exactly
        int t  = u & 63;
        int h2 = (u >> 6) & 1;
        int lp = u >> 7;
        int gl = lb + lp - PAD_;
        bool ok = (gl >= 0) && (gl < L_);
        short8 hv, lv;
        #pragma unroll
        for (int jj = 0; jj < 8; ++jj) {
            int cin = h2 * 8 + jj;
            float v = (ok && cin < CIN)
                ? x[(((size_t)b * CIN + cin) * L_ + gl) * T_ + t] : 0.0f;
            ushort hb = bf16_hi(v);
            ushort lo = bf16_hi(v - bf16_back(hb));
            hv[jj] = (short)hb;
            lv[jj] = (short)lo;
        }
        int nt = t >> 4, t15 = t & 15;
        int base = lp * 2048 + nt * 256 + h2 * 128 + t15 * 8;
        *(short8*)&S[base]        = hv;              // cp=0 (hi)
        *(short8*)&S[base + 1024] = lv;              // cp=1 (lo)
    }
    __syncthreads();

    int t15 = lane & 15;
    int h2l = (lane >> 4) & 1;
    int kqh = lane >> 5;

    float4v acc[4][4];                               // constant indices ONLY
    #pragma unroll
    for (int i = 0; i < 4; ++i)
        #pragma unroll
        for (int jn = 0; jn < 4; ++jn)
            acc[i][jn] = (float4v){0.0f, 0.0f, 0.0f, 0.0f};

    #pragma unroll
    for (int ks = 0; ks < 4; ++ks) {
        int dtap = ks * 2 + kqh;
        int lpr  = (dtap == 7) ? 0 : (wl + dtap);    // dl==7: A is zero, row 0 is finite
        int rb   = lpr * 2048 + h2l * 128 + t15 * 8;
        short8 bh[4], bl[4];
        #pragma unroll
        for (int nt = 0; nt < 4; ++nt) {
            bh[nt] = *(const short8*)&S[rb + nt * 256];
            bl[nt] = *(const short8*)&S[rb + nt * 256 + 1024];
        }
        #pragma unroll
        for (int mf = 0; mf < 4; ++mf) {
            const ushort* ap = w1f + ((size_t)(ks * 4 + mf) * 64 + lane) * 8;
            short8 ah = *(const short8*)ap;
            short8 al = *(const short8*)(ap + 8192);     // cp=1 half
            #pragma unroll
            for (int nt = 0; nt < 4; ++nt) {
                acc[mf][nt] = __builtin_amdgcn_mfma_f32_16x16x32_bf16(ah, bh[nt], acc[mf][nt], 0, 0, 0);
                acc[mf][nt] = __builtin_amdgcn_mfma_f32_16x16x32_bf16(al, bh[nt], acc[mf][nt], 0, 0, 0);
                acc[mf][nt] = __builtin_amdgcn_mfma_f32_16x16x32_bf16(ah, bl[nt], acc[mf][nt], 0, 0, 0);
            }
        }
    }

    // spike <=> conv + b1 >= TH1/GAIN = 0.25 (LIF1 tau=1 is memoryless).
    int l  = lb + wl;
    int kq = lane >> 4;
    #pragma unroll
    for (int h = 0; h < 2; ++h) {
        float4v be0 = *(const float4v*)&b1[h * 32 + kq * 4];
        float4v be1 = *(const float4v*)&b1[h * 32 + 16 + kq * 4];
        #pragma unroll
        for (int nt = 0; nt < 4; ++nt) {
            uint s0 = (acc[2 * h][nt][0] + be0[0] >= 0.25f) ? 0x3F80u : 0u;
            uint s1 = (acc[2 * h][nt][1] + be0[1] >= 0.25f) ? 0x3F80u : 0u;
            uint s2 = (acc[2 * h][nt][2] + be0[2] >= 0.25f) ? 0x3F80u : 0u;
            uint s3 = (acc[2 * h][nt][3] + be0[3] >= 0.25f) ? 0x3F80u : 0u;
            uint s4 = (acc[2 * h + 1][nt][0] + be1[0] >= 0.25f) ? 0x3F80u : 0u;
            uint s5 = (acc[2 * h + 1][nt][1] + be1[1] >= 0.25f) ? 0x3F80u : 0u;
            uint s6 = (acc[2 * h + 1][nt][2] + be1[2] >= 0.25f) ? 0x3F80u : 0u;
            uint s7 = (acc[2 * h + 1][nt][3] + be1[3] >= 0.25f) ? 0x3F80u : 0u;
            uint4 u4 = { s0 | (s1 << 16), s2 | (s3 << 16),
                         s4 | (s5 << 16), s6 | (s7 << 16) };
            size_t off = ((((size_t)b * L_ + l) * 2 + h) * T_ + (nt * 16 + t15)) * 32 + kq * 8;
            *(uint4*)&s1t[off] = u4;
        }
    }
}

// ---------------- K2: conv2 (bf16 MFMA) + fused LIF2 + fused avg-pool ----------------
// R11: R9/R10-exact (288-292 us — best of all structural variants). DMA staging
// (global_load_lds, pre-swizzled source), sequential h phases, 2 barriers/h.
// INVARIANT: acc[][] indexed with compile-time constants ONLY (scratch-demotion hazard).
__global__ __launch_bounds__(512, 2) void k2_conv2_lif(const ushort* __restrict__ s1t,
                                                       const ushort* __restrict__ w2hi,
                                                       const float* __restrict__ b2,
                                                       float* __restrict__ pool,
                                                       const ushort* __restrict__ zp) {
    __shared__ __align__(16) unsigned char lds_raw[40960];
    ushort* S = (ushort*)lds_raw;   // stage: [lp10][nt4][kq4][t15 16][j8] = 40,960 B (one h)
    int tid    = threadIdx.x;
    int wv     = tid >> 6;          // 0..7
    int lane   = tid & 63;
    int wn     = wv >> 1;           // l offset 0..3: l = lb + wn
    int wm     = wv & 1;            // m half: c2 in [wm*64, wm*64+64)
    int b      = blockIdx.y;
    int bx     = blockIdx.x;
    int swz    = ((bx & 7) << 5) | (bx >> 3);   // bijective XCD swizzle (256 = 8*32)
    int lb     = swz * 4;
    int lane15 = lane & 15;
    int kq     = lane >> 4;
    int srcoff = lane15 * 32 + (lane >> 4) * 8; // pre-swizzled DMA source (ushorts)

    float4v acc[4][4];             // [m-frag][n-frag], 64 regs — constant indices ONLY
    #pragma unroll
    for (int i = 0; i < 4; ++i)
        #pragma unroll
        for (int j = 0; j < 4; ++j)
            acc[i][j] = (float4v){0.0f, 0.0f, 0.0f, 0.0f};

    #pragma unroll 1
    for (int h = 0; h < 2; ++h) {
        __syncthreads();           // S reads of previous h done
        // DMA stage: rows lb-3..lb+6 (10 x 4KB); wave-uniform row loop, 4 insts/row
        #pragma unroll
        for (int r0 = 0; r0 < 2; ++r0) {
            int r = r0 * 8 + wv;
            if (r < 10) {
                int gl = lb + r - PAD_;
                const ushort* srow = (gl >= 0 && gl < L_)
                    ? &s1t[(((size_t)b * L_ + gl) * 2 + h) * 2048] : zp;
                const ushort* s = srow + srcoff;
                ushort* d = &S[r * 2048];
                GLOAD_LDS(s,        d);
                GLOAD_LDS(s + 512,  d + 512);
                GLOAD_LDS(s + 1024, d + 1024);
                GLOAD_LDS(s + 1536, d + 1536);
            }
        }
        __syncthreads();           // emits vmcnt(0) drain: DMA complete for all waves
        #pragma unroll 2
        for (int kk = 0; kk < K_; ++kk) {
            int lp = wn + kk;            // staged row feeding output l = lb+wn at tap kk
            short8 bf[4];
            #pragma unroll
            for (int nt = 0; nt < 4; ++nt)   // lane-linear 2KB frag -> conflict-free b128
                bf[nt] = *(const short8*)&S[lp * 2048 + nt * 512 + lane * 8];
            #pragma unroll
            for (int mf = 0; mf < 4; ++mf) {
                int aoff = (((kk * 2 + h) * 8 + wm * 4 + mf) * 64 + lane) * 8;  // 32-bit
                short8 ahi = *(const short8*)&w2hi[aoff];
                #pragma unroll
                for (int nt = 0; nt < 4; ++nt)
                    acc[mf][nt] = __builtin_amdgcn_mfma_f32_16x16x32_bf16(ahi, bf[nt], acc[mf][nt], 0, 0, 0);
            }
        }
    }
    __syncthreads();    // all S reads done before epilogue overlays the region

    // ---- epilogue: streaming transpose (one nt = 16 t-rows at a time) + LIF2 scan ----
    // E[t15 16][68]: b128 stores slot=(lane15+kq+4mfl)%8 -> 8 lanes/slot, conflict-free;
    // reads bank (4t+lane)%32 -> 2-way (free). All 64 lanes scan (c2 = wm*64 + lane).
    // Scan: v' = A*v + (E*Cs + D), A = 1-1/0.9, Cs = 2/0.9, D = bias*2/0.9.
    float* E = ((float*)lds_raw) + wv * 1088;
    int c2v = wm * 64 + lane;
    const float Af = 1.0f - 1.0f / 0.9f;
    const float Cs = 2.0f / 0.9f;
    float D = b2[c2v] * Cs;
    float v = 0.0f;
    uint cnt = 0u;
    #pragma unroll
    for (int nt = 0; nt < 4; ++nt) {
        *(float4v*)&E[lane15 * 68 + 0 * 16 + kq * 4] = acc[0][nt];   // D: col t = nt*16+lane15
        *(float4v*)&E[lane15 * 68 + 1 * 16 + kq * 4] = acc[1][nt];   //    row c2l = mfl*16+kq*4+r
        *(float4v*)&E[lane15 * 68 + 2 * 16 + kq * 4] = acc[2][nt];
        *(float4v*)&E[lane15 * 68 + 3 * 16 + kq * 4] = acc[3][nt];
        __builtin_amdgcn_s_waitcnt(0);           // wave-local LDS RAW
        #pragma unroll
        for (int tt = 0; tt < 16; ++tt) {
            float e = fmaf(E[tt * 68 + lane], Cs, D);
            v = fmaf(Af, v, e);
            bool sp = (v >= 0.5f);
            cnt += sp ? 1u : 0u;
            v = sp ? 0.0f : v;
        }
        __builtin_amdgcn_s_waitcnt(0);           // reads done before next nt overwrites
    }
    atomicAdd(&pool[b * C2_ + c2v], (float)cnt);  // integer-valued: exact, order-free
}

// ---------------- K3: fc on pooled [B][C2] (pool already summed over l,t) ----------------
__global__ __launch_bounds__(128) void k3_fc(const float* __restrict__ pool,
                                             const float* __restrict__ fcw,
                                             const float* __restrict__ fcb,
                                             float* __restrict__ out) {
    int i = threadIdx.x;          // 128 = B*4 outputs
    int b = i >> 2, c = i & 3;
    float o = fcb[c];
    #pragma unroll 8
    for (int c2 = 0; c2 < C2_; ++c2)
        o = fmaf(fcw[c * C2_ + c2], pool[b * C2_ + c2] * (1.0f / 65536.0f), o);
    out[b * 4 + c] = o;
}

extern "C" void kernel_launch(void* const* d_in, const int* in_sizes, int n_in,
                              void* d_out, int out_size, void* d_ws, size_t ws_size,
                              hipStream_t stream) {
    const float* x   = (const float*)d_in[0];
    const float* w1  = (const float*)d_in[1];
    const float* b1  = (const float*)d_in[2];
    const float* w2  = (const float*)d_in[3];
    const float* b2  = (const float*)d_in[4];
    const float* fcw = (const float*)d_in[5];
    const float* fcb = (const float*)d_in[6];
    float* out = (float*)d_out;

    char* ws = (char*)d_ws;
    ushort* s1t  = (ushort*)(ws + WS_S1T);
    ushort* w2h  = (ushort*)(ws + WS_W2HI);
    ushort* w1f  = (ushort*)(ws + WS_W1F);
    float*  pool = (float*)(ws + WS_POOL);
    ushort* zp   = (ushort*)(ws + WS_ZP);

    k0_prep<<<dim3((C2_ * K_ * C1_ + 255) / 256), dim3(256), 0, stream>>>(w2, w2h, w1, w1f, pool, zp);
    k1_conv1_mfma<<<dim3(L_ / 4, B_), dim3(256), 0, stream>>>(x, w1f, b1, s1t);
    k2_conv2_lif<<<dim3(L_ / 4, B_), dim3(512), 0, stream>>>(s1t, w2h, b2, pool, zp);
    k3_fc<<<dim3(1), dim3(128), 0, stream>>>(pool, fcw, fcb, out);
}

// Round 12
// 483.477 us; speedup vs baseline: 1.2970x; 1.0713x over previous
//
#include <hip/hip_runtime.h>
#include <hip/hip_bf16.h>
#include <cstdint>

#define B_   32
#define CIN  12
#define L_   1024
#define T_   64
#define C1_  64
#define C2_  128
#define K_   7
#define PAD_ 3

typedef __attribute__((ext_vector_type(8))) short short8;
typedef __attribute__((ext_vector_type(4))) float float4v;

// ---- workspace layout (bytes) ----
// s1b : BIT-PACKED spikes [B][L][h2][dword64]  = 16,777,216  (bit j of byte(kq) = k~=kq*8+j;
//       dword index = t15*4+kq, byte n within dword = nt)
// w2hi: bf16 A-frag-linear            = 114,688
// w1f : bf16 A-frag-linear [cp2][ks4][mf4][lane64][j8] = 32,768
// pool: f32  [B][C2]                  = 16,384   (fused avg-pool accumulator, zeroed by K0)
#define WS_S1B   0ull
#define WS_W2HI  16777216ull
#define WS_W1F   (WS_W2HI + 114688ull)
#define WS_POOL  (WS_W1F + 32768ull)

static __device__ __forceinline__ ushort bf16_hi(float f) {
    __hip_bfloat16 h = __float2bfloat16(f);
    ushort u; __builtin_memcpy(&u, &h, 2); return u;
}
static __device__ __forceinline__ float bf16_back(ushort u) {
    __hip_bfloat16 h; __builtin_memcpy(&h, &u, 2); return __bfloat162float(h);
}

// expand one spike byte (bits j=0..7 -> k~ positions) to 8 bf16 {0, 1.0} packed in uint4
static __device__ __forceinline__ uint4 expand_byte(uint byte) {
    uint4 e;
    e.x = ((byte & 1u)   ? 0x3F80u : 0u) | ((byte & 2u)   ? 0x3F800000u : 0u);
    e.y = ((byte & 4u)   ? 0x3F80u : 0u) | ((byte & 8u)   ? 0x3F800000u : 0u);
    e.z = ((byte & 16u)  ? 0x3F80u : 0u) | ((byte & 32u)  ? 0x3F800000u : 0u);
    e.w = ((byte & 64u)  ? 0x3F80u : 0u) | ((byte & 128u) ? 0x3F800000u : 0u);
    return e;
}

// ---------------- K0: w2 + w1 prep merged (one dispatch), + zero pool ----------------
// w2: c1 contraction order PERMUTED within each 32-chunk to match K1's bit order:
// k~ = kq*8 + e*4 + r  <->  c1r = e*16 + kq*4 + r  (e = c1r>>4).
// w1: hi/lo split, A-frag-linear, contraction k = dl*16 + cin (slots 12..15 zero).
__global__ __launch_bounds__(256) void k0_prep(const float* __restrict__ w2,
                                               ushort* __restrict__ w2hi,
                                               const float* __restrict__ w1,
                                               ushort* __restrict__ w1f,
                                               float* __restrict__ pool) {
    int i = blockIdx.x * 256 + threadIdx.x;
    if (i < B_ * C2_) pool[i] = 0.0f;            // stream-ordered before K2's atomics
    if (i < 16384) {                             // ---- w1f: [cp2][ks4][mf4][lane64][j8]
        int j    = i & 7;
        int lane = (i >> 3) & 63;
        int mf   = (i >> 9) & 3;
        int ks   = (i >> 11) & 3;
        int cp   = i >> 13;
        int k    = ks * 32 + (lane >> 4) * 8 + j;
        int dl   = k >> 4;
        int slot = k & 15;
        int c1   = mf * 16 + (lane & 15);
        float v  = (slot < CIN && dl < K_) ? w1[(c1 * CIN + slot) * K_ + dl] : 0.0f;
        ushort hi = bf16_hi(v);
        float  rem = v - bf16_back(hi);
        ushort lo = bf16_hi(rem);
        w1f[i] = cp ? lo : hi;
    }
    if (i >= C2_ * K_ * C1_) return;             // ---- w2hi
    int c2 = i / (K_ * C1_);
    int r_ = i % (K_ * C1_);
    int kk = r_ / C1_;
    int c1 = r_ % C1_;
    float w = w2[(c2 * C1_ + c1) * K_ + kk];
    ushort uh = bf16_hi(w);
    int h    = c1 >> 5;
    int c1r  = c1 & 31;
    int e    = c1r >> 4;
    int kq   = (c1r >> 2) & 3;
    int rr   = c1r & 3;
    int j    = e * 4 + rr;
    int mt   = c2 >> 4;
    int lane = kq * 16 + (c2 & 15);
    int o    = ((((kk * 2 + h) * 8 + mt) * 64) + lane) * 8 + j;
    w2hi[o] = uh;
}

// ---------------- K1: conv1 via bf16 MFMA (hi/lo split) + LIF1 spike -> s1b (bits) ----------------
// R12: epilogue stores BIT-PACKED spikes — 2 dword stores/lane (was 8 uint4).
// WRITE_SIZE 262,144 KB -> 16,384 KB; the 268 MB s1t stream was k1's dominant cost.
// Spike VALUES unchanged (encoding only) -> absmax must stay exactly 0.00390625.
__global__ __launch_bounds__(256, 3) void k1_conv1_mfma(const float* __restrict__ x,
                                                        const ushort* __restrict__ w1f,
                                                        const float* __restrict__ b1,
                                                        uint* __restrict__ s1b) {
    __shared__ __align__(16) ushort S[10 * 2048];    // 40,960 B
    int tid  = threadIdx.x;
    int lane = tid & 63;
    int wl   = tid >> 6;
    int b    = blockIdx.y;
    int bx   = blockIdx.x;
    int swz  = ((bx & 7) << 5) | (bx >> 3);          // XCD swizzle, bijective (256 = 8*32)
    int lb   = swz * 4;

    #pragma unroll
    for (int it = 0; it < 5; ++it) {
        int u  = it * 256 + tid;                     // 10*2*64 = 1280 exactly
        int t  = u & 63;
        int h2 = (u >> 6) & 1;
        int lp = u >> 7;
        int gl = lb + lp - PAD_;
        bool ok = (gl >= 0) && (gl < L_);
        short8 hv, lv;
        #pragma unroll
        for (int jj = 0; jj < 8; ++jj) {
            int cin = h2 * 8 + jj;
            float v = (ok && cin < CIN)
                ? x[(((size_t)b * CIN + cin) * L_ + gl) * T_ + t] : 0.0f;
            ushort hb = bf16_hi(v);
            ushort lo = bf16_hi(v - bf16_back(hb));
            hv[jj] = (short)hb;
            lv[jj] = (short)lo;
        }
        int nt = t >> 4, t15 = t & 15;
        int base = lp * 2048 + nt * 256 + h2 * 128 + t15 * 8;
        *(short8*)&S[base]        = hv;              // cp=0 (hi)
        *(short8*)&S[base + 1024] = lv;              // cp=1 (lo)
    }
    __syncthreads();

    int t15 = lane & 15;
    int h2l = (lane >> 4) & 1;
    int kqh = lane >> 5;

    float4v acc[4][4];                               // constant indices ONLY
    #pragma unroll
    for (int i = 0; i < 4; ++i)
        #pragma unroll
        for (int jn = 0; jn < 4; ++jn)
            acc[i][jn] = (float4v){0.0f, 0.0f, 0.0f, 0.0f};

    #pragma unroll
    for (int ks = 0; ks < 4; ++ks) {
        int dtap = ks * 2 + kqh;
        int lpr  = (dtap == 7) ? 0 : (wl + dtap);    // dl==7: A is zero, row 0 is finite
        int rb   = lpr * 2048 + h2l * 128 + t15 * 8;
        short8 bh[4], bl[4];
        #pragma unroll
        for (int nt = 0; nt < 4; ++nt) {
            bh[nt] = *(const short8*)&S[rb + nt * 256];
            bl[nt] = *(const short8*)&S[rb + nt * 256 + 1024];
        }
        #pragma unroll
        for (int mf = 0; mf < 4; ++mf) {
            const ushort* ap = w1f + ((size_t)(ks * 4 + mf) * 64 + lane) * 8;
            short8 ah = *(const short8*)ap;
            short8 al = *(const short8*)(ap + 8192);     // cp=1 half
            #pragma unroll
            for (int nt = 0; nt < 4; ++nt) {
                acc[mf][nt] = __builtin_amdgcn_mfma_f32_16x16x32_bf16(ah, bh[nt], acc[mf][nt], 0, 0, 0);
                acc[mf][nt] = __builtin_amdgcn_mfma_f32_16x16x32_bf16(al, bh[nt], acc[mf][nt], 0, 0, 0);
                acc[mf][nt] = __builtin_amdgcn_mfma_f32_16x16x32_bf16(ah, bl[nt], acc[mf][nt], 0, 0, 0);
            }
        }
    }

    // spike <=> conv + b1 >= TH1/GAIN = 0.25 (LIF1 tau=1 is memoryless).
    // bit j of byte(kq) = k~ = kq*8+j; j = e*4+r (s0..s3 -> e=0, s4..s7 -> e=1).
    int l  = lb + wl;
    int kq = lane >> 4;
    #pragma unroll
    for (int h = 0; h < 2; ++h) {
        float4v be0 = *(const float4v*)&b1[h * 32 + kq * 4];
        float4v be1 = *(const float4v*)&b1[h * 32 + 16 + kq * 4];
        uint w = 0u;
        #pragma unroll
        for (int nt = 0; nt < 4; ++nt) {
            uint byte =
                ((acc[2 * h][nt][0]     + be0[0] >= 0.25f) ? 1u   : 0u) |
                ((acc[2 * h][nt][1]     + be0[1] >= 0.25f) ? 2u   : 0u) |
                ((acc[2 * h][nt][2]     + be0[2] >= 0.25f) ? 4u   : 0u) |
                ((acc[2 * h][nt][3]     + be0[3] >= 0.25f) ? 8u   : 0u) |
                ((acc[2 * h + 1][nt][0] + be1[0] >= 0.25f) ? 16u  : 0u) |
                ((acc[2 * h + 1][nt][1] + be1[1] >= 0.25f) ? 32u  : 0u) |
                ((acc[2 * h + 1][nt][2] + be1[2] >= 0.25f) ? 64u  : 0u) |
                ((acc[2 * h + 1][nt][3] + be1[3] >= 0.25f) ? 128u : 0u);
            w |= byte << (8 * nt);
        }
        s1b[((size_t)(b * L_ + l) * 2 + h) * 64 + t15 * 4 + kq] = w;   // coalesced 256B/wave
    }
}

// ---------------- K2: conv2 (bf16 MFMA) + fused LIF2 + fused avg-pool ----------------
// R12: stage = load-dword + bit-expand (replaces R11's DMA; source is now 16.8 MB,
// L2/L3-resident). Thread (lp, w=t15*4+kq) reads one dword (4 nt-bytes), expands each
// byte to uint4 of bf16, stores to the IDENTICAL S layout (lane-linear per nt,
// conflict-free). Inner loop / epilogue / barriers byte-identical to R11.
// INVARIANT: acc[][] indexed with compile-time constants ONLY (scratch-demotion hazard).
__global__ __launch_bounds__(512, 2) void k2_conv2_lif(const uint* __restrict__ s1b,
                                                       const ushort* __restrict__ w2hi,
                                                       const float* __restrict__ b2,
                                                       float* __restrict__ pool) {
    __shared__ __align__(16) unsigned char lds_raw[40960];
    ushort* S = (ushort*)lds_raw;   // stage: [lp10][nt4][kq4][t15 16][j8] = 40,960 B (one h)
    int tid    = threadIdx.x;
    int wv     = tid >> 6;          // 0..7
    int lane   = tid & 63;
    int wn     = wv >> 1;           // l offset 0..3: l = lb + wn
    int wm     = wv & 1;            // m half: c2 in [wm*64, wm*64+64)
    int b      = blockIdx.y;
    int bx     = blockIdx.x;
    int swz    = ((bx & 7) << 5) | (bx >> 3);   // bijective XCD swizzle (256 = 8*32)
    int lb     = swz * 4;
    int lane15 = lane & 15;
    int kq     = lane >> 4;

    float4v acc[4][4];             // [m-frag][n-frag], 64 regs — constant indices ONLY
    #pragma unroll
    for (int i = 0; i < 4; ++i)
        #pragma unroll
        for (int j = 0; j < 4; ++j)
            acc[i][j] = (float4v){0.0f, 0.0f, 0.0f, 0.0f};

    #pragma unroll 1
    for (int h = 0; h < 2; ++h) {
        __syncthreads();           // S reads of previous h done
        // stage: rows lb-3..lb+6; 640 tasks = (lp 10) x (w 64); 1 dword + expand each
        #pragma unroll
        for (int it = 0; it < 2; ++it) {
            int u = it * 512 + tid;
            if (u < 640) {
                int lp = u >> 6, w = u & 63;
                int gl = lb + lp - PAD_;
                uint bits = (gl >= 0 && gl < L_)
                    ? s1b[((size_t)(b * L_ + gl) * 2 + h) * 64 + w] : 0u;
                int st15 = w >> 2, skq = w & 3;
                int base = lp * 2048 + skq * 128 + st15 * 8;
                *(uint4*)&S[base]        = expand_byte(bits & 0xffu);
                *(uint4*)&S[base + 512]  = expand_byte((bits >> 8) & 0xffu);
                *(uint4*)&S[base + 1024] = expand_byte((bits >> 16) & 0xffu);
                *(uint4*)&S[base + 1536] = expand_byte(bits >> 24);
            }
        }
        __syncthreads();           // stage complete for all waves
        #pragma unroll 2
        for (int kk = 0; kk < K_; ++kk) {
            int lp = wn + kk;            // staged row feeding output l = lb+wn at tap kk
            short8 bf[4];
            #pragma unroll
            for (int nt = 0; nt < 4; ++nt)   // lane-linear 2KB frag -> conflict-free b128
                bf[nt] = *(const short8*)&S[lp * 2048 + nt * 512 + lane * 8];
            #pragma unroll
            for (int mf = 0; mf < 4; ++mf) {
                int aoff = (((kk * 2 + h) * 8 + wm * 4 + mf) * 64 + lane) * 8;  // 32-bit
                short8 ahi = *(const short8*)&w2hi[aoff];
                #pragma unroll
                for (int nt = 0; nt < 4; ++nt)
                    acc[mf][nt] = __builtin_amdgcn_mfma_f32_16x16x32_bf16(ahi, bf[nt], acc[mf][nt], 0, 0, 0);
            }
        }
    }
    __syncthreads();    // all S reads done before epilogue overlays the region

    // ---- epilogue: streaming transpose (one nt = 16 t-rows at a time) + LIF2 scan ----
    // E[t15 16][68]: b128 stores slot=(lane15+kq+4mfl)%8 -> 8 lanes/slot, conflict-free;
    // reads bank (4t+lane)%32 -> 2-way (free). All 64 lanes scan (c2 = wm*64 + lane).
    // Scan: v' = A*v + (E*Cs + D), A = 1-1/0.9, Cs = 2/0.9, D = bias*2/0.9.
    float* E = ((float*)lds_raw) + wv * 1088;
    int c2v = wm * 64 + lane;
    const float Af = 1.0f - 1.0f / 0.9f;
    const float Cs = 2.0f / 0.9f;
    float D = b2[c2v] * Cs;
    float v = 0.0f;
    uint cnt = 0u;
    #pragma unroll
    for (int nt = 0; nt < 4; ++nt) {
        *(float4v*)&E[lane15 * 68 + 0 * 16 + kq * 4] = acc[0][nt];   // D: col t = nt*16+lane15
        *(float4v*)&E[lane15 * 68 + 1 * 16 + kq * 4] = acc[1][nt];   //    row c2l = mfl*16+kq*4+r
        *(float4v*)&E[lane15 * 68 + 2 * 16 + kq * 4] = acc[2][nt];
        *(float4v*)&E[lane15 * 68 + 3 * 16 + kq * 4] = acc[3][nt];
        __builtin_amdgcn_s_waitcnt(0);           // wave-local LDS RAW
        #pragma unroll
        for (int tt = 0; tt < 16; ++tt) {
            float e = fmaf(E[tt * 68 + lane], Cs, D);
            v = fmaf(Af, v, e);
            bool sp = (v >= 0.5f);
            cnt += sp ? 1u : 0u;
            v = sp ? 0.0f : v;
        }
        __builtin_amdgcn_s_waitcnt(0);           // reads done before next nt overwrites
    }
    atomicAdd(&pool[b * C2_ + c2v], (float)cnt);  // integer-valued: exact, order-free
}

// ---------------- K3: fc on pooled [B][C2] (pool already summed over l,t) ----------------
__global__ __launch_bounds__(128) void k3_fc(const float* __restrict__ pool,
                                             const float* __restrict__ fcw,
                                             const float* __restrict__ fcb,
                                             float* __restrict__ out) {
    int i = threadIdx.x;          // 128 = B*4 outputs
    int b = i >> 2, c = i & 3;
    float o = fcb[c];
    #pragma unroll 8
    for (int c2 = 0; c2 < C2_; ++c2)
        o = fmaf(fcw[c * C2_ + c2], pool[b * C2_ + c2] * (1.0f / 65536.0f), o);
    out[b * 4 + c] = o;
}

extern "C" void kernel_launch(void* const* d_in, const int* in_sizes, int n_in,
                              void* d_out, int out_size, void* d_ws, size_t ws_size,
                              hipStream_t stream) {
    const float* x   = (const float*)d_in[0];
    const float* w1  = (const float*)d_in[1];
    const float* b1  = (const float*)d_in[2];
    const float* w2  = (const float*)d_in[3];
    const float* b2  = (const float*)d_in[4];
    const float* fcw = (const float*)d_in[5];
    const float* fcb = (const float*)d_in[6];
    float* out = (float*)d_out;

    char* ws = (char*)d_ws;
    uint*   s1b  = (uint*)(ws + WS_S1B);
    ushort* w2h  = (ushort*)(ws + WS_W2HI);
    ushort* w1f  = (ushort*)(ws + WS_W1F);
    float*  pool = (float*)(ws + WS_POOL);

    k0_prep<<<dim3((C2_ * K_ * C1_ + 255) / 256), dim3(256), 0, stream>>>(w2, w2h, w1, w1f, pool);
    k1_conv1_mfma<<<dim3(L_ / 4, B_), dim3(256), 0, stream>>>(x, w1f, b1, s1b);
    k2_conv2_lif<<<dim3(L_ / 4, B_), dim3(512), 0, stream>>>(s1b, w2h, b2, pool);
    k3_fc<<<dim3(1), dim3(128), 0, stream>>>(pool, fcw, fcb, out);
}